// Round 14
// baseline (588.285 us; speedup 1.0000x reference)
//
#include <hip/hip_runtime.h>
#include <hip/hip_fp16.h>
#include <cstddef>

#define Wn 12
#define Nn 20000
#define Cn 64
#define En 320000
#define OFFS_STRIDE 20032
#define NBKT 79
#define BCAP 4672

typedef _Float16 h4v __attribute__((ext_vector_type(4)));
typedef _Float16 h8v __attribute__((ext_vector_type(8)));
typedef float    f4v __attribute__((ext_vector_type(4)));

__device__ __forceinline__ float elu_f(float v) {
    return v > 0.f ? v : (expf(v) - 1.f);
}

// ---------------------------------------------------------------------------
// Weight prep: pack all 4 kernel sizes (sig+gate) into MFMA B-fragment order.
// ---------------------------------------------------------------------------
__global__ __launch_bounds__(256) void wprep_kernel(
    const float* __restrict__ sw1, const float* __restrict__ gw1,
    const float* __restrict__ sw3, const float* __restrict__ gw3,
    const float* __restrict__ sw5, const float* __restrict__ gw5,
    const float* __restrict__ sw7, const float* __restrict__ gw7,
    __half* __restrict__ dst)
{
    const int i = blockIdx.x * 256 + threadIdx.x;   // 32768 total
    if (i >= 32768) return;
    const int j    = i & 7;
    const int lane = (i >> 3) & 63;
    const int slot = i >> 9;                        // 0..63
    int g, loc;
    if (slot < 4)       { g = 0; loc = slot; }
    else if (slot < 16) { g = 1; loc = slot - 4; }
    else if (slot < 36) { g = 2; loc = slot - 16; }
    else                { g = 3; loc = slot - 36; }
    const int k   = 2 * g + 1;
    const int nks = 2 * k;                          // k-steps per path
    const int sg  = (loc >= nks) ? 1 : 0;          // 0 = sig, 1 = gate
    const int s   = loc - sg * nks;
    const int t   = s >> 1;                         // tap 0..k-1
    const int ih  = s & 1;                          // ic half
    const int oc  = lane & 15;
    const int ic  = ih * 32 + (lane >> 4) * 8 + j;
    const float* src;
    switch (g * 2 + sg) {
      case 0: src = sw1; break; case 1: src = gw1; break;
      case 2: src = sw3; break; case 3: src = gw3; break;
      case 4: src = sw5; break; case 5: src = gw5; break;
      case 6: src = sw7; break; default: src = gw7; break;
    }
    dst[i] = __float2half(src[(oc * 64 + ic) * k + t]);
}

// ---------------------------------------------------------------------------
// GCN weight prep: pack gcn_w (both hops) into MFMA B-fragment fp16 layout.
// ---------------------------------------------------------------------------
__global__ __launch_bounds__(256) void gwprep_kernel(
    const float* __restrict__ gcnw, __half* __restrict__ dst)
{
    const int i = blockIdx.x * 256 + threadIdx.x;   // 98304 total
    if (i >= 98304) return;
    const int j      = i & 7;
    const int lane   = (i >> 3) & 63;
    const int kh     = (i >> 9) & 1;
    const int octile = (i >> 10) & 3;
    const int hw     = i >> 12;
    const int ic = (lane >> 4) * 8 + j + kh * 32;
    const int oc = octile * 16 + (lane & 15);
    dst[i] = __float2half(gcnw[(size_t)hw * 4096 + ic * 64 + oc]);
}

// ---------------------------------------------------------------------------
// One oc-group of the inception conv via MFMA. B-fragments read directly
// from global wT (64 KB, L2-resident). (256,4) bound: no spill (round-8).
// ---------------------------------------------------------------------------
template<int G>
__device__ __forceinline__ void mfma_group(
    const __half* __restrict__ wTg,    // global fragment-packed weights, group G
    const __half* __restrict__ xsh,
    const float* __restrict__ sb, const float* __restrict__ gb,
    float* __restrict__ h, int nb, int tid)
{
    constexpr int NKS = 2 * (2 * G + 1);
    const int lane = tid & 63;
    const int wv   = tid >> 6;                 // 0..3
    const int node16 = lane & 15;
    const int abase = node16 * 128;
    const int swz   = (lane & 7) << 4;
    const int aoff0 = abase + ((0  + (lane >> 4) * 16) ^ swz);
    const int aoff1 = abase + ((64 + (lane >> 4) * 16) ^ swz);

    f4v accS[3], accG[3];
    #pragma unroll
    for (int m = 0; m < 3; ++m) {
        accS[m] = (f4v){0.f, 0.f, 0.f, 0.f};
        accG[m] = (f4v){0.f, 0.f, 0.f, 0.f};
    }

    #pragma unroll
    for (int s2 = 0; s2 < 2 * G + 1; ++s2) {   // dw = s2 - G
        const int dw = s2 - G;
        #pragma unroll
        for (int ih = 0; ih < 2; ++ih) {
            const int s = s2 * 2 + ih;
            const h8v bs = *(const h8v*)&wTg[(s * 64 + lane) * 8];
            const h8v bg = *(const h8v*)&wTg[((NKS + s) * 64 + lane) * 8];
            const int laneoff = ih ? aoff1 : aoff0;
            #pragma unroll
            for (int m = 0; m < 3; ++m) {
                const int w  = wv * 3 + m;
                const int wp = w + dw;
                if (wp >= 0 && wp < Wn) {      // wave-uniform
                    const h8v a = *(const h8v*)((const char*)xsh + wp * 2048 + laneoff);
                    accS[m] = __builtin_amdgcn_mfma_f32_16x16x32_f16(a, bs, accS[m], 0, 0, 0);
                    accG[m] = __builtin_amdgcn_mfma_f32_16x16x32_f16(a, bg, accG[m], 0, 0, 0);
                }
            }
        }
    }

    const float sbv = sb[node16];
    const float gbv = gb[node16];
    const int oc = G * 16 + node16;
    #pragma unroll
    for (int m = 0; m < 3; ++m) {
        const int w = wv * 3 + m;
        #pragma unroll
        for (int r = 0; r < 4; ++r) {
            const int node = (lane >> 4) * 4 + r;
            const float sv = accS[m][r] + sbv;
            const float gv = accG[m][r] + gbv;
            const float rv = sv > 0.f ? sv : 0.f;
            const float sg = 1.f / (1.f + expf(-gv));
            h[((size_t)w * Nn + nb + node) * Cn + oc] = rv * sg;
        }
    }
}

// ---------------------------------------------------------------------------
// Inception gated temporal conv, MFMA v4: GROUP-PAIR SPLIT. Round-13
// counters: 157 µs with MfmaUtil 3.4%, VALUBusy 25%, Occ 32.6% — latency/
// serialization-bound (1250 blocks, 4 serial G-phases). Split the 4 groups
// over 2 blocks (gp): 2512 blocks, 2 phases each, 2x waves, 6 blocks/CU by
// LDS. XCD-pairing swizzle: sibling blocks (same node tile) get linear ids
// = (nb%8) + 8*(2*(nb/8)+gp)  ->  same id mod 8 -> same XCD, adjacent in
// queue -> the 2nd block's x-stage hits L2 (no 61 MB HBM re-read).
// ---------------------------------------------------------------------------
__global__ __launch_bounds__(256, 4) void inception_mfma_kernel(
    const float* __restrict__ x,
    const float* __restrict__ sb1, const float* __restrict__ gb1,
    const float* __restrict__ sb3, const float* __restrict__ gb3,
    const float* __restrict__ sb5, const float* __restrict__ gb5,
    const float* __restrict__ sb7, const float* __restrict__ gb7,
    const __half* __restrict__ wT,
    float* __restrict__ h)
{
    __shared__ __align__(16) __half xsh[12 * 16 * 64];   // 24,576 B
    const int b   = blockIdx.x;
    const int r8  = b & 7, q8 = b >> 3;
    const int gp  = q8 & 1;
    const int nbi = (q8 >> 1) * 8 + r8;
    if (nbi >= 1250) return;
    const int nb  = nbi * 16;
    const int tid = threadIdx.x;

    const float4* xg = (const float4*)x;
    for (int i = tid; i < 3072; i += 256) {
        const int w = i >> 8, r = i & 255, node = r >> 4, c4 = r & 15;
        const float4 v = xg[((size_t)w * Nn + nb + node) * 16 + c4];
        h4v p = { (_Float16)v.x, (_Float16)v.y, (_Float16)v.z, (_Float16)v.w };
        const int off = w * 2048 + node * 128 + (((c4 << 3)) ^ ((node & 7) << 4));
        *(h4v*)((char*)xsh + off) = p;
    }
    __syncthreads();
    if (gp == 0) {
        mfma_group<0>(wT,         xsh, sb1, gb1, h, nb, tid);
        mfma_group<1>(wT + 2048,  xsh, sb3, gb3, h, nb, tid);
    } else {
        mfma_group<2>(wT + 8192,  xsh, sb5, gb5, h, nb, tid);
        mfma_group<3>(wT + 18432, xsh, sb7, gb7, h, nb, tid);
    }
}

// ---------------------------------------------------------------------------
// Per-window (N x 64) @ (64 x 64) matmul via MFMA, v2: NO LDS. The A-frag
// is 8 consecutive fp32 of one H row -> two float4 global loads + inline
// cvt per fragment. B-frags from prepacked gwp (L2-resident). Tail guarded.
// ---------------------------------------------------------------------------
__global__ __launch_bounds__(256) void mm_mfma_kernel(
    const float* __restrict__ h, const __half* __restrict__ gwp,
    __half* __restrict__ t)
{
    const int w    = blockIdx.y;
    const int nb   = blockIdx.x * 64;
    const int tid  = threadIdx.x;
    const int lane = tid & 63;
    const int wv   = tid >> 6;                 // wave owns nodes wv*16..+16
    const int node = nb + wv * 16 + (lane & 15);
    const int nc   = (node < Nn) ? node : (Nn - 1);
    const float* hrow = h + ((size_t)w * Nn + nc) * 64 + (lane >> 4) * 8;

    const float4 q0a = *(const float4*)&hrow[0];
    const float4 q0b = *(const float4*)&hrow[4];
    const float4 q1a = *(const float4*)&hrow[32];
    const float4 q1b = *(const float4*)&hrow[36];
    const h8v a0 = { (_Float16)q0a.x, (_Float16)q0a.y, (_Float16)q0a.z, (_Float16)q0a.w,
                     (_Float16)q0b.x, (_Float16)q0b.y, (_Float16)q0b.z, (_Float16)q0b.w };
    const h8v a1 = { (_Float16)q1a.x, (_Float16)q1a.y, (_Float16)q1a.z, (_Float16)q1a.w,
                     (_Float16)q1b.x, (_Float16)q1b.y, (_Float16)q1b.z, (_Float16)q1b.w };

    const int node0 = nb + wv * 16 + (lane >> 4) * 4;
    #pragma unroll
    for (int ot = 0; ot < 4; ++ot) {
        const h8v b0 = *(const h8v*)&gwp[(((w * 4 + ot) * 2 + 0) * 64 + lane) * 8];
        const h8v b1 = *(const h8v*)&gwp[(((w * 4 + ot) * 2 + 1) * 64 + lane) * 8];
        f4v acc = (f4v){0.f, 0.f, 0.f, 0.f};
        acc = __builtin_amdgcn_mfma_f32_16x16x32_f16(a0, b0, acc, 0, 0, 0);
        acc = __builtin_amdgcn_mfma_f32_16x16x32_f16(a1, b1, acc, 0, 0, 0);
        const int oc = ot * 16 + (lane & 15);
        #pragma unroll
        for (int r = 0; r < 4; ++r) {
            const int nd = node0 + r;
            if (nd < Nn)
                t[((size_t)w * Nn + nd) * Cn + oc] = __float2half(acc[r]);
        }
    }
}

// ---------------------------------------------------------------------------
// Bucketed sort, phase A: bin 2560 edges/block into 79 coarse dst-buckets
// (dst>>8). Line-granular HBM writes via per-bucket contiguous runs.
// ---------------------------------------------------------------------------
__global__ __launch_bounds__(256) void bucketA_kernel(
    const int* __restrict__ ei, const float* __restrict__ ew,
    int* __restrict__ bcur, uint2* __restrict__ bstr)
{
    const int w   = blockIdx.y;
    const int tid = threadIdx.x;
    __shared__ uint2 compact[2560];
    __shared__ unsigned char bkid[2560];
    __shared__ int rcnt[NBKT], rbase[NBKT], sbase[NBKT];
    __shared__ int sc[128];

    const int* eis = ei + (size_t)w * 2 * En;
    const float* ews = ew + (size_t)w * En;
    const int e0 = blockIdx.x * 2560;

    if (tid < NBKT) rcnt[tid] = 0;
    __syncthreads();

    int myb[10], myr[10];
    uint2 mye[10];
    #pragma unroll
    for (int it = 0; it < 10; ++it) {
        const int e = e0 + it * 256 + tid;
        const int s = eis[e];
        const int d = eis[En + e];
        const float wt = ews[e];
        const int bk = d >> 8;
        myb[it] = bk;
        mye[it].x = (unsigned)s | ((unsigned)(d & 255) << 16);
        mye[it].y = __float_as_uint(wt);
        myr[it] = atomicAdd(&rcnt[bk], 1);
    }
    __syncthreads();
    if (tid < 128) sc[tid] = (tid < NBKT) ? rcnt[tid] : 0;
    __syncthreads();
    #pragma unroll
    for (int dlt = 1; dlt < 128; dlt <<= 1) {
        int t = (tid < 128 && tid >= dlt) ? sc[tid - dlt] : 0;
        __syncthreads();
        if (tid < 128) sc[tid] += t;
        __syncthreads();
    }
    if (tid < NBKT) {
        rbase[tid] = sc[tid] - rcnt[tid];                       // excl within block
        sbase[tid] = atomicAdd(&bcur[w * 80 + tid], rcnt[tid]); // segment in stream
    }
    __syncthreads();
    #pragma unroll
    for (int it = 0; it < 10; ++it) {
        const int p = rbase[myb[it]] + myr[it];
        compact[p] = mye[it];
        bkid[p] = (unsigned char)myb[it];
    }
    __syncthreads();
    for (int i = tid; i < 2560; i += 256) {
        const int bk = bkid[i];
        int off = sbase[bk] + (i - rbase[bk]);
        if (off >= BCAP) off = BCAP - 1;   // ~9 sigma guard, never expected
        bstr[((size_t)w * NBKT + bk) * BCAP + off] = compact[i];
    }
}

// ---------------------------------------------------------------------------
// Tiny scan over the 12 x 79 bucket counts -> exclusive bucket bases.
// ---------------------------------------------------------------------------
__global__ __launch_bounds__(768) void bscan_kernel(
    const int* __restrict__ bcur, int* __restrict__ bbase)
{
    const int lane = threadIdx.x & 63;
    const int w    = threadIdx.x >> 6;   // 0..11
    const int c0 = (lane < NBKT) ? bcur[w * 80 + lane] : 0;
    int s = c0;
    #pragma unroll
    for (int d = 1; d < 64; d <<= 1) {
        int t = __shfl_up(s, d);
        if (lane >= d) s += t;
    }
    const int tot0 = __shfl(s, 63);
    const int c1 = (lane + 64 < NBKT) ? bcur[w * 80 + 64 + lane] : 0;
    int s1 = c1;
    #pragma unroll
    for (int d = 1; d < 64; d <<= 1) {
        int t = __shfl_up(s1, d);
        if (lane >= d) s1 += t;
    }
    s1 += tot0;
    bbase[w * 80 + lane] = s - c0;
    if (lane + 64 < NBKT) bbase[w * 80 + 64 + lane] = s1 - c1;
}

// ---------------------------------------------------------------------------
// Bucketed sort, phase B: counting-sort one bucket, emit pairs + CSR offs.
// ---------------------------------------------------------------------------
__global__ __launch_bounds__(256) void bucketB_kernel(
    const uint2* __restrict__ bstr, const int* __restrict__ bcur,
    const int* __restrict__ bbase, int* __restrict__ offs,
    float2* __restrict__ pairs)
{
    const int bk = blockIdx.x, w = blockIdx.y;
    const int tid = threadIdx.x;
    __shared__ uint2 sorted[BCAP];
    __shared__ int lhist[256], lbase[256], wsum[4];
    int n = bcur[w * 80 + bk];
    if (n > BCAP) n = BCAP;
    const int gbase = bbase[w * 80 + bk];
    const uint2* src = bstr + ((size_t)w * NBKT + bk) * BCAP;

    lhist[tid] = 0;
    __syncthreads();

    constexpr int MAXE = (BCAP + 255) / 256;   // 19
    uint2 mye[MAXE];
    short myd[MAXE], myr[MAXE];
    #pragma unroll
    for (int it = 0; it < MAXE; ++it) {
        const int i = tid + it * 256;
        if (i < n) {
            const uint2 e = src[i];
            mye[it] = e;
            const int dl = (e.x >> 16) & 255;
            myd[it] = (short)dl;
            myr[it] = (short)atomicAdd(&lhist[dl], 1);
        }
    }
    __syncthreads();
    {
        const int lane = tid & 63, wv = tid >> 6;
        const int v = lhist[tid];
        int sum = v;
        #pragma unroll
        for (int dlt = 1; dlt < 64; dlt <<= 1) {
            int t = __shfl_up(sum, dlt);
            if (lane >= dlt) sum += t;
        }
        if (lane == 63) wsum[wv] = sum;
        __syncthreads();
        if (tid < 4) {
            int o = wsum[tid], s2 = o;
            #pragma unroll
            for (int dlt = 1; dlt < 4; dlt <<= 1) {
                int t = __shfl_up(s2, dlt);
                if (tid >= dlt) s2 += t;
            }
            wsum[tid] = s2 - o;            // exclusive across waves
        }
        __syncthreads();
        const int be = wsum[wv] + sum - v; // exclusive per-dst base
        lbase[tid] = be;
        const int d = bk * 256 + tid;
        if (d < Nn) offs[w * OFFS_STRIDE + d] = gbase + be;
        if (bk == NBKT - 1 && tid == 0) offs[w * OFFS_STRIDE + Nn] = En;
    }
    __syncthreads();
    #pragma unroll
    for (int it = 0; it < MAXE; ++it) {
        const int i = tid + it * 256;
        if (i < n)
            sorted[lbase[myd[it]] + myr[it]] = mye[it];
    }
    __syncthreads();
    float2* pw = pairs + (size_t)w * En + gbase;
    for (int i = tid; i < n; i += 256) {
        const uint2 e = sorted[i];
        pw[i] = make_float2(__int_as_float((int)(e.x & 0xFFFFu)), __uint_as_float(e.y));
    }
}

// ---------------------------------------------------------------------------
// Aggregation v3r (measured best: ~110-115 µs): 16 lanes/edge x 4
// edge-subgroups, 4 channels/lane, 2-deep unroll, 32-bit element offsets.
// Round-12 lesson: manual batched prefetch regressed; compiler pipelines
// this loop already.
// ---------------------------------------------------------------------------
template<bool LAST>
__global__ __launch_bounds__(256) void agg_kernel(
    const __half* __restrict__ t, const float2* __restrict__ pairs,
    const int* __restrict__ offs, const float* __restrict__ b,
    const float* __restrict__ x, float* __restrict__ out)
{
    const int blk = blockIdx.x;
    const int r = blk & 7, q = blk >> 3;
    int w, ng;
    if (q < 5000) { w = r; ng = q; }
    else { int q2 = q - 5000; w = 8 + (r >> 1); ng = q2 * 2 + (r & 1); }

    const int d    = ng * 4 + (threadIdx.x >> 6);
    const int lane = threadIdx.x & 63;
    const int eg   = lane >> 4;           // edge subgroup 0..3
    const int c4   = lane & 15;           // channel quad (4 channels)
    const int* ow  = offs + w * OFFS_STRIDE;
    const int beg = ow[d];
    const int end = ow[d + 1];
    const float2* pw = pairs + (size_t)w * En;
    const __half* twc = t + (size_t)w * Nn * Cn + c4 * 4;

    float a0 = 0.f, a1 = 0.f, a2 = 0.f, a3 = 0.f;
    int i = beg;
    for (; i + 8 <= end; i += 8) {
        const float2 p0 = pw[i + eg];
        const float2 p1 = pw[i + 4 + eg];
        const uint2 r0 = *(const uint2*)(twc + ((unsigned)__float_as_int(p0.x) << 6));
        const uint2 r1 = *(const uint2*)(twc + ((unsigned)__float_as_int(p1.x) << 6));
        const float2 fa01 = __half22float2(*(const __half2*)&r0.x);
        const float2 fa23 = __half22float2(*(const __half2*)&r0.y);
        const float2 fb01 = __half22float2(*(const __half2*)&r1.x);
        const float2 fb23 = __half22float2(*(const __half2*)&r1.y);
        a0 = fmaf(p0.y, fa01.x, a0);
        a1 = fmaf(p0.y, fa01.y, a1);
        a2 = fmaf(p0.y, fa23.x, a2);
        a3 = fmaf(p0.y, fa23.y, a3);
        a0 = fmaf(p1.y, fb01.x, a0);
        a1 = fmaf(p1.y, fb01.y, a1);
        a2 = fmaf(p1.y, fb23.x, a2);
        a3 = fmaf(p1.y, fb23.y, a3);
    }
    if (i + 4 <= end) {
        const float2 p0 = pw[i + eg];
        const uint2 r0 = *(const uint2*)(twc + ((unsigned)__float_as_int(p0.x) << 6));
        const float2 fa01 = __half22float2(*(const __half2*)&r0.x);
        const float2 fa23 = __half22float2(*(const __half2*)&r0.y);
        a0 = fmaf(p0.y, fa01.x, a0);
        a1 = fmaf(p0.y, fa01.y, a1);
        a2 = fmaf(p0.y, fa23.x, a2);
        a3 = fmaf(p0.y, fa23.y, a3);
        i += 4;
    }
    if (i + eg < end) {
        const float2 p0 = pw[i + eg];
        const uint2 r0 = *(const uint2*)(twc + ((unsigned)__float_as_int(p0.x) << 6));
        const float2 fa01 = __half22float2(*(const __half2*)&r0.x);
        const float2 fa23 = __half22float2(*(const __half2*)&r0.y);
        a0 = fmaf(p0.y, fa01.x, a0);
        a1 = fmaf(p0.y, fa01.y, a1);
        a2 = fmaf(p0.y, fa23.x, a2);
        a3 = fmaf(p0.y, fa23.y, a3);
    }

    a0 += __shfl_xor(a0, 16); a0 += __shfl_xor(a0, 32);
    a1 += __shfl_xor(a1, 16); a1 += __shfl_xor(a1, 32);
    a2 += __shfl_xor(a2, 16); a2 += __shfl_xor(a2, 32);
    a3 += __shfl_xor(a3, 16); a3 += __shfl_xor(a3, 32);

    if (eg == 0) {
        const float4 bv = *(const float4*)&b[w * Cn + c4 * 4];
        float v0 = elu_f(a0 + bv.x);
        float v1 = elu_f(a1 + bv.y);
        float v2 = elu_f(a2 + bv.z);
        float v3 = elu_f(a3 + bv.w);
        const size_t oi = ((size_t)w * Nn + d) * Cn + c4 * 4;
        if (LAST) {
            const float4 xv = *(const float4*)&x[oi];
            v0 += xv.x; v1 += xv.y; v2 += xv.z; v3 += xv.w;
        }
        *(float4*)&out[oi] = make_float4(v0, v1, v2, v3);
    }
}

// ---------------------------------------------------------------------------
// ws layout (floats):
//   [0)          pairs : 7,680,000
//   [7,680,000)  offs  :   240,384 (int)  -- written by bucketB
//   [7,920,384)  bcur  :   240,000 (int)  -- [0,960) counts, [1024,1984) bases
//   [8,160,384)  wTreg :   240,000 (int)  -- wT (32768 halfs) + gwp (98304
//                                            halfs at +32768) = 260 KB used
//   [8,400,384)  H     : 15,360,000      -- doubles as bstr (35.4 MB) before
//                                           inception overwrites it (in-order)
// ---------------------------------------------------------------------------
extern "C" void kernel_launch(void* const* d_in, const int* in_sizes, int n_in,
                              void* d_out, int out_size, void* d_ws, size_t ws_size,
                              hipStream_t stream)
{
    const float* x    = (const float*)d_in[0];
    const int*   ei   = (const int*)d_in[1];
    const float* ew   = (const float*)d_in[2];
    const float* sw1  = (const float*)d_in[3];
    const float* sb1  = (const float*)d_in[4];
    const float* gw1  = (const float*)d_in[5];
    const float* gb1  = (const float*)d_in[6];
    const float* sw3  = (const float*)d_in[7];
    const float* sb3  = (const float*)d_in[8];
    const float* gw3  = (const float*)d_in[9];
    const float* gb3  = (const float*)d_in[10];
    const float* sw5  = (const float*)d_in[11];
    const float* sb5  = (const float*)d_in[12];
    const float* gw5  = (const float*)d_in[13];
    const float* gb5  = (const float*)d_in[14];
    const float* sw7  = (const float*)d_in[15];
    const float* sb7  = (const float*)d_in[16];
    const float* gw7  = (const float*)d_in[17];
    const float* gb7  = (const float*)d_in[18];
    const float* gcnw = (const float*)d_in[19];
    const float* gcnb = (const float*)d_in[20];
    float* out = (float*)d_out;
    __half* Th = (__half*)d_out;

    const size_t WNC = (size_t)Wn * Nn * Cn;
    const int mm_grid = (Nn + 63) / 64;    // 313 — tail block guarded

    float2* pairs = (float2*)d_ws;
    int*    offs  = (int*)((float*)d_ws + 7680000);
    int*    bcur  = offs + 240384;
    int*    bbase = bcur + 1024;
    __half* wT    = (__half*)(bcur + 240000);
    __half* gwp   = wT + 32768;
    float*  H     = (float*)((int*)(bcur + 240000) + 240000);
    uint2*  bstr  = (uint2*)H;             // phase-A bucket streams (dead after B)

    // --- sort preamble ---
    hipMemsetAsync(bcur, 0, (size_t)Wn * 80 * sizeof(int), stream);
    bucketA_kernel<<<dim3(En / 2560, Wn), 256, 0, stream>>>(ei, ew, bcur, bstr);
    bscan_kernel<<<1, 768, 0, stream>>>(bcur, bbase);
    bucketB_kernel<<<dim3(NBKT, Wn), 256, 0, stream>>>(bstr, bcur, bbase, offs, pairs);

    // --- weight fragment packs (fp16) ---
    wprep_kernel<<<128, 256, 0, stream>>>(sw1, gw1, sw3, gw3, sw5, gw5, sw7, gw7, wT);
    gwprep_kernel<<<384, 256, 0, stream>>>(gcnw, gwp);

    // --- feature path (MFMA, group-pair split: 2512 blocks) ---
    inception_mfma_kernel<<<2512, 256, 0, stream>>>(
        x, sb1, gb1, sb3, gb3, sb5, gb5, sb7, gb7, wT, H);

    // hop 0
    mm_mfma_kernel<<<dim3(mm_grid, Wn), 256, 0, stream>>>(H, gwp, Th);
    agg_kernel<false><<<60000, 256, 0, stream>>>(
        Th, pairs, offs, gcnb, nullptr, H);

    // hop 1
    mm_mfma_kernel<<<dim3(mm_grid, Wn), 256, 0, stream>>>(
        H, gwp + (size_t)Wn * 4096, Th);
    agg_kernel<true><<<60000, 256, 0, stream>>>(
        Th, pairs, offs, gcnb + (size_t)Wn * Cn, x, H);
    hipMemcpyAsync(out, H, WNC * sizeof(float), hipMemcpyDeviceToDevice, stream);
}

// Round 15
// 543.651 us; speedup vs baseline: 1.0821x; 1.0821x over previous
//
#include <hip/hip_runtime.h>
#include <hip/hip_fp16.h>
#include <cstddef>

#define Wn 12
#define Nn 20000
#define Cn 64
#define En 320000
#define OFFS_STRIDE 20032
#define NBKT 79
#define BCAP 4672

typedef _Float16 h4v __attribute__((ext_vector_type(4)));
typedef _Float16 h8v __attribute__((ext_vector_type(8)));
typedef float    f4v __attribute__((ext_vector_type(4)));

__device__ __forceinline__ float elu_f(float v) {
    return v > 0.f ? v : (expf(v) - 1.f);
}

// ---------------------------------------------------------------------------
// Weight prep: pack all 4 kernel sizes (sig+gate) into MFMA B-fragment order.
// ---------------------------------------------------------------------------
__global__ __launch_bounds__(256) void wprep_kernel(
    const float* __restrict__ sw1, const float* __restrict__ gw1,
    const float* __restrict__ sw3, const float* __restrict__ gw3,
    const float* __restrict__ sw5, const float* __restrict__ gw5,
    const float* __restrict__ sw7, const float* __restrict__ gw7,
    __half* __restrict__ dst)
{
    const int i = blockIdx.x * 256 + threadIdx.x;   // 32768 total
    if (i >= 32768) return;
    const int j    = i & 7;
    const int lane = (i >> 3) & 63;
    const int slot = i >> 9;                        // 0..63
    int g, loc;
    if (slot < 4)       { g = 0; loc = slot; }
    else if (slot < 16) { g = 1; loc = slot - 4; }
    else if (slot < 36) { g = 2; loc = slot - 16; }
    else                { g = 3; loc = slot - 36; }
    const int k   = 2 * g + 1;
    const int nks = 2 * k;                          // k-steps per path
    const int sg  = (loc >= nks) ? 1 : 0;          // 0 = sig, 1 = gate
    const int s   = loc - sg * nks;
    const int t   = s >> 1;                         // tap 0..k-1
    const int ih  = s & 1;                          // ic half
    const int oc  = lane & 15;
    const int ic  = ih * 32 + (lane >> 4) * 8 + j;
    const float* src;
    switch (g * 2 + sg) {
      case 0: src = sw1; break; case 1: src = gw1; break;
      case 2: src = sw3; break; case 3: src = gw3; break;
      case 4: src = sw5; break; case 5: src = gw5; break;
      case 6: src = sw7; break; default: src = gw7; break;
    }
    dst[i] = __float2half(src[(oc * 64 + ic) * k + t]);
}

// ---------------------------------------------------------------------------
// GCN weight prep: pack gcn_w (both hops) into MFMA B-fragment fp16 layout.
// ---------------------------------------------------------------------------
__global__ __launch_bounds__(256) void gwprep_kernel(
    const float* __restrict__ gcnw, __half* __restrict__ dst)
{
    const int i = blockIdx.x * 256 + threadIdx.x;   // 98304 total
    if (i >= 98304) return;
    const int j      = i & 7;
    const int lane   = (i >> 3) & 63;
    const int kh     = (i >> 9) & 1;
    const int octile = (i >> 10) & 3;
    const int hw     = i >> 12;
    const int ic = (lane >> 4) * 8 + j + kh * 32;
    const int oc = octile * 16 + (lane & 15);
    dst[i] = __float2half(gcnw[(size_t)hw * 4096 + ic * 64 + oc]);
}

// ---------------------------------------------------------------------------
// One oc-group of the inception conv via MFMA. B-fragments read directly
// from global wT (64 KB, L2-resident). (256,4) bound: no spill (round-8).
// ---------------------------------------------------------------------------
template<int G>
__device__ __forceinline__ void mfma_group(
    const __half* __restrict__ wTg,    // global fragment-packed weights, group G
    const __half* __restrict__ xsh,
    const float* __restrict__ sb, const float* __restrict__ gb,
    float* __restrict__ h, int nb, int tid)
{
    constexpr int NKS = 2 * (2 * G + 1);
    const int lane = tid & 63;
    const int wv   = tid >> 6;                 // 0..3
    const int node16 = lane & 15;
    const int abase = node16 * 128;
    const int swz   = (lane & 7) << 4;
    const int aoff0 = abase + ((0  + (lane >> 4) * 16) ^ swz);
    const int aoff1 = abase + ((64 + (lane >> 4) * 16) ^ swz);

    f4v accS[3], accG[3];
    #pragma unroll
    for (int m = 0; m < 3; ++m) {
        accS[m] = (f4v){0.f, 0.f, 0.f, 0.f};
        accG[m] = (f4v){0.f, 0.f, 0.f, 0.f};
    }

    #pragma unroll
    for (int s2 = 0; s2 < 2 * G + 1; ++s2) {   // dw = s2 - G
        const int dw = s2 - G;
        #pragma unroll
        for (int ih = 0; ih < 2; ++ih) {
            const int s = s2 * 2 + ih;
            const h8v bs = *(const h8v*)&wTg[(s * 64 + lane) * 8];
            const h8v bg = *(const h8v*)&wTg[((NKS + s) * 64 + lane) * 8];
            const int laneoff = ih ? aoff1 : aoff0;
            #pragma unroll
            for (int m = 0; m < 3; ++m) {
                const int w  = wv * 3 + m;
                const int wp = w + dw;
                if (wp >= 0 && wp < Wn) {      // wave-uniform
                    const h8v a = *(const h8v*)((const char*)xsh + wp * 2048 + laneoff);
                    accS[m] = __builtin_amdgcn_mfma_f32_16x16x32_f16(a, bs, accS[m], 0, 0, 0);
                    accG[m] = __builtin_amdgcn_mfma_f32_16x16x32_f16(a, bg, accG[m], 0, 0, 0);
                }
            }
        }
    }

    const float sbv = sb[node16];
    const float gbv = gb[node16];
    const int oc = G * 16 + node16;
    #pragma unroll
    for (int m = 0; m < 3; ++m) {
        const int w = wv * 3 + m;
        #pragma unroll
        for (int r = 0; r < 4; ++r) {
            const int node = (lane >> 4) * 4 + r;
            const float sv = accS[m][r] + sbv;
            const float gv = accG[m][r] + gbv;
            const float rv = sv > 0.f ? sv : 0.f;
            const float sg = 1.f / (1.f + expf(-gv));
            h[((size_t)w * Nn + nb + node) * Cn + oc] = rv * sg;
        }
    }
}

// ---------------------------------------------------------------------------
// Inception gated temporal conv, MFMA (round-13 form — measured best total).
// ROUND-14 LESSON: splitting the 4 oc-groups across 2 blocks made each H
// row (256 B) be assembled by two blocks -> partial-line writeback (WRITE
// 104 -> 140 MB) and a net total regression despite the kernel itself being
// 14 µs faster. Full-row writes win.
// ---------------------------------------------------------------------------
__global__ __launch_bounds__(256, 4) void inception_mfma_kernel(
    const float* __restrict__ x,
    const float* __restrict__ sb1, const float* __restrict__ gb1,
    const float* __restrict__ sb3, const float* __restrict__ gb3,
    const float* __restrict__ sb5, const float* __restrict__ gb5,
    const float* __restrict__ sb7, const float* __restrict__ gb7,
    const __half* __restrict__ wT,
    float* __restrict__ h)
{
    __shared__ __align__(16) __half xsh[12 * 16 * 64];   // 24,576 B
    const int tid = threadIdx.x;
    const int nb  = blockIdx.x * 16;

    const float4* xg = (const float4*)x;
    for (int i = tid; i < 3072; i += 256) {
        const int w = i >> 8, r = i & 255, node = r >> 4, c4 = r & 15;
        const float4 v = xg[((size_t)w * Nn + nb + node) * 16 + c4];
        h4v p = { (_Float16)v.x, (_Float16)v.y, (_Float16)v.z, (_Float16)v.w };
        const int off = w * 2048 + node * 128 + (((c4 << 3)) ^ ((node & 7) << 4));
        *(h4v*)((char*)xsh + off) = p;
    }
    __syncthreads();
    mfma_group<0>(wT,         xsh, sb1, gb1, h, nb, tid);
    mfma_group<1>(wT + 2048,  xsh, sb3, gb3, h, nb, tid);
    mfma_group<2>(wT + 8192,  xsh, sb5, gb5, h, nb, tid);
    mfma_group<3>(wT + 18432, xsh, sb7, gb7, h, nb, tid);
}

// ---------------------------------------------------------------------------
// Per-window (N x 64) @ (64 x 64) matmul via MFMA, v2: NO LDS. The A-frag
// is 8 consecutive fp32 of one H row -> two float4 global loads + inline
// cvt per fragment. B-frags from prepacked gwp (L2-resident). Tail guarded.
// ---------------------------------------------------------------------------
__global__ __launch_bounds__(256) void mm_mfma_kernel(
    const float* __restrict__ h, const __half* __restrict__ gwp,
    __half* __restrict__ t)
{
    const int w    = blockIdx.y;
    const int nb   = blockIdx.x * 64;
    const int tid  = threadIdx.x;
    const int lane = tid & 63;
    const int wv   = tid >> 6;                 // wave owns nodes wv*16..+16
    const int node = nb + wv * 16 + (lane & 15);
    const int nc   = (node < Nn) ? node : (Nn - 1);
    const float* hrow = h + ((size_t)w * Nn + nc) * 64 + (lane >> 4) * 8;

    const float4 q0a = *(const float4*)&hrow[0];
    const float4 q0b = *(const float4*)&hrow[4];
    const float4 q1a = *(const float4*)&hrow[32];
    const float4 q1b = *(const float4*)&hrow[36];
    const h8v a0 = { (_Float16)q0a.x, (_Float16)q0a.y, (_Float16)q0a.z, (_Float16)q0a.w,
                     (_Float16)q0b.x, (_Float16)q0b.y, (_Float16)q0b.z, (_Float16)q0b.w };
    const h8v a1 = { (_Float16)q1a.x, (_Float16)q1a.y, (_Float16)q1a.z, (_Float16)q1a.w,
                     (_Float16)q1b.x, (_Float16)q1b.y, (_Float16)q1b.z, (_Float16)q1b.w };

    const int node0 = nb + wv * 16 + (lane >> 4) * 4;
    #pragma unroll
    for (int ot = 0; ot < 4; ++ot) {
        const h8v b0 = *(const h8v*)&gwp[(((w * 4 + ot) * 2 + 0) * 64 + lane) * 8];
        const h8v b1 = *(const h8v*)&gwp[(((w * 4 + ot) * 2 + 1) * 64 + lane) * 8];
        f4v acc = (f4v){0.f, 0.f, 0.f, 0.f};
        acc = __builtin_amdgcn_mfma_f32_16x16x32_f16(a0, b0, acc, 0, 0, 0);
        acc = __builtin_amdgcn_mfma_f32_16x16x32_f16(a1, b1, acc, 0, 0, 0);
        const int oc = ot * 16 + (lane & 15);
        #pragma unroll
        for (int r = 0; r < 4; ++r) {
            const int nd = node0 + r;
            if (nd < Nn)
                t[((size_t)w * Nn + nd) * Cn + oc] = __float2half(acc[r]);
        }
    }
}

// ---------------------------------------------------------------------------
// Bucketed sort, phase A: bin 2560 edges/block into 79 coarse dst-buckets
// (dst>>8). Line-granular HBM writes via per-bucket contiguous runs.
// ---------------------------------------------------------------------------
__global__ __launch_bounds__(256) void bucketA_kernel(
    const int* __restrict__ ei, const float* __restrict__ ew,
    int* __restrict__ bcur, uint2* __restrict__ bstr)
{
    const int w   = blockIdx.y;
    const int tid = threadIdx.x;
    __shared__ uint2 compact[2560];
    __shared__ unsigned char bkid[2560];
    __shared__ int rcnt[NBKT], rbase[NBKT], sbase[NBKT];
    __shared__ int sc[128];

    const int* eis = ei + (size_t)w * 2 * En;
    const float* ews = ew + (size_t)w * En;
    const int e0 = blockIdx.x * 2560;

    if (tid < NBKT) rcnt[tid] = 0;
    __syncthreads();

    int myb[10], myr[10];
    uint2 mye[10];
    #pragma unroll
    for (int it = 0; it < 10; ++it) {
        const int e = e0 + it * 256 + tid;
        const int s = eis[e];
        const int d = eis[En + e];
        const float wt = ews[e];
        const int bk = d >> 8;
        myb[it] = bk;
        mye[it].x = (unsigned)s | ((unsigned)(d & 255) << 16);
        mye[it].y = __float_as_uint(wt);
        myr[it] = atomicAdd(&rcnt[bk], 1);
    }
    __syncthreads();
    if (tid < 128) sc[tid] = (tid < NBKT) ? rcnt[tid] : 0;
    __syncthreads();
    #pragma unroll
    for (int dlt = 1; dlt < 128; dlt <<= 1) {
        int t = (tid < 128 && tid >= dlt) ? sc[tid - dlt] : 0;
        __syncthreads();
        if (tid < 128) sc[tid] += t;
        __syncthreads();
    }
    if (tid < NBKT) {
        rbase[tid] = sc[tid] - rcnt[tid];                       // excl within block
        sbase[tid] = atomicAdd(&bcur[w * 80 + tid], rcnt[tid]); // segment in stream
    }
    __syncthreads();
    #pragma unroll
    for (int it = 0; it < 10; ++it) {
        const int p = rbase[myb[it]] + myr[it];
        compact[p] = mye[it];
        bkid[p] = (unsigned char)myb[it];
    }
    __syncthreads();
    for (int i = tid; i < 2560; i += 256) {
        const int bk = bkid[i];
        int off = sbase[bk] + (i - rbase[bk]);
        if (off >= BCAP) off = BCAP - 1;   // ~9 sigma guard, never expected
        bstr[((size_t)w * NBKT + bk) * BCAP + off] = compact[i];
    }
}

// ---------------------------------------------------------------------------
// Tiny scan over the 12 x 79 bucket counts -> exclusive bucket bases.
// ---------------------------------------------------------------------------
__global__ __launch_bounds__(768) void bscan_kernel(
    const int* __restrict__ bcur, int* __restrict__ bbase)
{
    const int lane = threadIdx.x & 63;
    const int w    = threadIdx.x >> 6;   // 0..11
    const int c0 = (lane < NBKT) ? bcur[w * 80 + lane] : 0;
    int s = c0;
    #pragma unroll
    for (int d = 1; d < 64; d <<= 1) {
        int t = __shfl_up(s, d);
        if (lane >= d) s += t;
    }
    const int tot0 = __shfl(s, 63);
    const int c1 = (lane + 64 < NBKT) ? bcur[w * 80 + 64 + lane] : 0;
    int s1 = c1;
    #pragma unroll
    for (int d = 1; d < 64; d <<= 1) {
        int t = __shfl_up(s1, d);
        if (lane >= d) s1 += t;
    }
    s1 += tot0;
    bbase[w * 80 + lane] = s - c0;
    if (lane + 64 < NBKT) bbase[w * 80 + 64 + lane] = s1 - c1;
}

// ---------------------------------------------------------------------------
// Bucketed sort, phase B: counting-sort one bucket, emit pairs + CSR offs.
// ---------------------------------------------------------------------------
__global__ __launch_bounds__(256) void bucketB_kernel(
    const uint2* __restrict__ bstr, const int* __restrict__ bcur,
    const int* __restrict__ bbase, int* __restrict__ offs,
    float2* __restrict__ pairs)
{
    const int bk = blockIdx.x, w = blockIdx.y;
    const int tid = threadIdx.x;
    __shared__ uint2 sorted[BCAP];
    __shared__ int lhist[256], lbase[256], wsum[4];
    int n = bcur[w * 80 + bk];
    if (n > BCAP) n = BCAP;
    const int gbase = bbase[w * 80 + bk];
    const uint2* src = bstr + ((size_t)w * NBKT + bk) * BCAP;

    lhist[tid] = 0;
    __syncthreads();

    constexpr int MAXE = (BCAP + 255) / 256;   // 19
    uint2 mye[MAXE];
    short myd[MAXE], myr[MAXE];
    #pragma unroll
    for (int it = 0; it < MAXE; ++it) {
        const int i = tid + it * 256;
        if (i < n) {
            const uint2 e = src[i];
            mye[it] = e;
            const int dl = (e.x >> 16) & 255;
            myd[it] = (short)dl;
            myr[it] = (short)atomicAdd(&lhist[dl], 1);
        }
    }
    __syncthreads();
    {
        const int lane = tid & 63, wv = tid >> 6;
        const int v = lhist[tid];
        int sum = v;
        #pragma unroll
        for (int dlt = 1; dlt < 64; dlt <<= 1) {
            int t = __shfl_up(sum, dlt);
            if (lane >= dlt) sum += t;
        }
        if (lane == 63) wsum[wv] = sum;
        __syncthreads();
        if (tid < 4) {
            int o = wsum[tid], s2 = o;
            #pragma unroll
            for (int dlt = 1; dlt < 4; dlt <<= 1) {
                int t = __shfl_up(s2, dlt);
                if (tid >= dlt) s2 += t;
            }
            wsum[tid] = s2 - o;            // exclusive across waves
        }
        __syncthreads();
        const int be = wsum[wv] + sum - v; // exclusive per-dst base
        lbase[tid] = be;
        const int d = bk * 256 + tid;
        if (d < Nn) offs[w * OFFS_STRIDE + d] = gbase + be;
        if (bk == NBKT - 1 && tid == 0) offs[w * OFFS_STRIDE + Nn] = En;
    }
    __syncthreads();
    #pragma unroll
    for (int it = 0; it < MAXE; ++it) {
        const int i = tid + it * 256;
        if (i < n)
            sorted[lbase[myd[it]] + myr[it]] = mye[it];
    }
    __syncthreads();
    float2* pw = pairs + (size_t)w * En + gbase;
    for (int i = tid; i < n; i += 256) {
        const uint2 e = sorted[i];
        pw[i] = make_float2(__int_as_float((int)(e.x & 0xFFFFu)), __uint_as_float(e.y));
    }
}

// ---------------------------------------------------------------------------
// Aggregation v3r (measured best): 16 lanes/edge x 4 edge-subgroups, 4
// channels/lane, 2-deep unroll, 32-bit element offsets.
// ---------------------------------------------------------------------------
template<bool LAST>
__global__ __launch_bounds__(256) void agg_kernel(
    const __half* __restrict__ t, const float2* __restrict__ pairs,
    const int* __restrict__ offs, const float* __restrict__ b,
    const float* __restrict__ x, float* __restrict__ out)
{
    const int blk = blockIdx.x;
    const int r = blk & 7, q = blk >> 3;
    int w, ng;
    if (q < 5000) { w = r; ng = q; }
    else { int q2 = q - 5000; w = 8 + (r >> 1); ng = q2 * 2 + (r & 1); }

    const int d    = ng * 4 + (threadIdx.x >> 6);
    const int lane = threadIdx.x & 63;
    const int eg   = lane >> 4;           // edge subgroup 0..3
    const int c4   = lane & 15;           // channel quad (4 channels)
    const int* ow  = offs + w * OFFS_STRIDE;
    const int beg = ow[d];
    const int end = ow[d + 1];
    const float2* pw = pairs + (size_t)w * En;
    const __half* twc = t + (size_t)w * Nn * Cn + c4 * 4;

    float a0 = 0.f, a1 = 0.f, a2 = 0.f, a3 = 0.f;
    int i = beg;
    for (; i + 8 <= end; i += 8) {
        const float2 p0 = pw[i + eg];
        const float2 p1 = pw[i + 4 + eg];
        const uint2 r0 = *(const uint2*)(twc + ((unsigned)__float_as_int(p0.x) << 6));
        const uint2 r1 = *(const uint2*)(twc + ((unsigned)__float_as_int(p1.x) << 6));
        const float2 fa01 = __half22float2(*(const __half2*)&r0.x);
        const float2 fa23 = __half22float2(*(const __half2*)&r0.y);
        const float2 fb01 = __half22float2(*(const __half2*)&r1.x);
        const float2 fb23 = __half22float2(*(const __half2*)&r1.y);
        a0 = fmaf(p0.y, fa01.x, a0);
        a1 = fmaf(p0.y, fa01.y, a1);
        a2 = fmaf(p0.y, fa23.x, a2);
        a3 = fmaf(p0.y, fa23.y, a3);
        a0 = fmaf(p1.y, fb01.x, a0);
        a1 = fmaf(p1.y, fb01.y, a1);
        a2 = fmaf(p1.y, fb23.x, a2);
        a3 = fmaf(p1.y, fb23.y, a3);
    }
    if (i + 4 <= end) {
        const float2 p0 = pw[i + eg];
        const uint2 r0 = *(const uint2*)(twc + ((unsigned)__float_as_int(p0.x) << 6));
        const float2 fa01 = __half22float2(*(const __half2*)&r0.x);
        const float2 fa23 = __half22float2(*(const __half2*)&r0.y);
        a0 = fmaf(p0.y, fa01.x, a0);
        a1 = fmaf(p0.y, fa01.y, a1);
        a2 = fmaf(p0.y, fa23.x, a2);
        a3 = fmaf(p0.y, fa23.y, a3);
        i += 4;
    }
    if (i + eg < end) {
        const float2 p0 = pw[i + eg];
        const uint2 r0 = *(const uint2*)(twc + ((unsigned)__float_as_int(p0.x) << 6));
        const float2 fa01 = __half22float2(*(const __half2*)&r0.x);
        const float2 fa23 = __half22float2(*(const __half2*)&r0.y);
        a0 = fmaf(p0.y, fa01.x, a0);
        a1 = fmaf(p0.y, fa01.y, a1);
        a2 = fmaf(p0.y, fa23.x, a2);
        a3 = fmaf(p0.y, fa23.y, a3);
    }

    a0 += __shfl_xor(a0, 16); a0 += __shfl_xor(a0, 32);
    a1 += __shfl_xor(a1, 16); a1 += __shfl_xor(a1, 32);
    a2 += __shfl_xor(a2, 16); a2 += __shfl_xor(a2, 32);
    a3 += __shfl_xor(a3, 16); a3 += __shfl_xor(a3, 32);

    if (eg == 0) {
        const float4 bv = *(const float4*)&b[w * Cn + c4 * 4];
        float v0 = elu_f(a0 + bv.x);
        float v1 = elu_f(a1 + bv.y);
        float v2 = elu_f(a2 + bv.z);
        float v3 = elu_f(a3 + bv.w);
        const size_t oi = ((size_t)w * Nn + d) * Cn + c4 * 4;
        if (LAST) {
            const float4 xv = *(const float4*)&x[oi];
            v0 += xv.x; v1 += xv.y; v2 += xv.z; v3 += xv.w;
        }
        *(float4*)&out[oi] = make_float4(v0, v1, v2, v3);
    }
}

// ---------------------------------------------------------------------------
// ws layout (floats):
//   [0)           pairs : 7,680,000
//   [7,680,000)   offs  :   240,384 (int)
//   [7,920,384)   bcur  :   240,000 (int)
//   [8,160,384)   wTreg :   240,000 (int)  -- wT + gwp fragment packs
//   [8,400,384)   H     : 15,360,000      -- doubles as bstr before inception
//   [23,760,384)  Th2   : 7,680,000       -- hop-1 fp16 t, ONLY if ws_size
//                                            >= 125.76 MB (runtime check);
//                                            enables direct agg->d_out write
//                                            (no final 61 MB D2D memcpy).
// ---------------------------------------------------------------------------
extern "C" void kernel_launch(void* const* d_in, const int* in_sizes, int n_in,
                              void* d_out, int out_size, void* d_ws, size_t ws_size,
                              hipStream_t stream)
{
    const float* x    = (const float*)d_in[0];
    const int*   ei   = (const int*)d_in[1];
    const float* ew   = (const float*)d_in[2];
    const float* sw1  = (const float*)d_in[3];
    const float* sb1  = (const float*)d_in[4];
    const float* gw1  = (const float*)d_in[5];
    const float* gb1  = (const float*)d_in[6];
    const float* sw3  = (const float*)d_in[7];
    const float* sb3  = (const float*)d_in[8];
    const float* gw3  = (const float*)d_in[9];
    const float* gb3  = (const float*)d_in[10];
    const float* sw5  = (const float*)d_in[11];
    const float* sb5  = (const float*)d_in[12];
    const float* gw5  = (const float*)d_in[13];
    const float* gb5  = (const float*)d_in[14];
    const float* sw7  = (const float*)d_in[15];
    const float* sb7  = (const float*)d_in[16];
    const float* gw7  = (const float*)d_in[17];
    const float* gb7  = (const float*)d_in[18];
    const float* gcnw = (const float*)d_in[19];
    const float* gcnb = (const float*)d_in[20];
    float* out = (float*)d_out;
    __half* Th = (__half*)d_out;

    const size_t WNC = (size_t)Wn * Nn * Cn;
    const int mm_grid = (Nn + 63) / 64;    // 313 — tail block guarded

    float2* pairs = (float2*)d_ws;
    int*    offs  = (int*)((float*)d_ws + 7680000);
    int*    bcur  = offs + 240384;
    int*    bbase = bcur + 1024;
    __half* wT    = (__half*)(bcur + 240000);
    __half* gwp   = wT + 32768;
    float*  H     = (float*)((int*)(bcur + 240000) + 240000);
    uint2*  bstr  = (uint2*)H;             // phase-A bucket streams (dead after B)

    // hop-1 t placement: dedicated ws region if it fits, else d_out + memcpy
    const size_t need_ws_bytes = (size_t)(23760384 + 7680000) * sizeof(float);
    const bool   direct_out    = ws_size >= need_ws_bytes;
    __half* Th2 = direct_out ? (__half*)((float*)d_ws + 23760384) : Th;

    // --- sort preamble ---
    hipMemsetAsync(bcur, 0, (size_t)Wn * 80 * sizeof(int), stream);
    bucketA_kernel<<<dim3(En / 2560, Wn), 256, 0, stream>>>(ei, ew, bcur, bstr);
    bscan_kernel<<<1, 768, 0, stream>>>(bcur, bbase);
    bucketB_kernel<<<dim3(NBKT, Wn), 256, 0, stream>>>(bstr, bcur, bbase, offs, pairs);

    // --- weight fragment packs (fp16) ---
    wprep_kernel<<<128, 256, 0, stream>>>(sw1, gw1, sw3, gw3, sw5, gw5, sw7, gw7, wT);
    gwprep_kernel<<<384, 256, 0, stream>>>(gcnw, gwp);

    // --- feature path (MFMA) ---
    inception_mfma_kernel<<<Nn / 16, 256, 0, stream>>>(
        x, sb1, gb1, sb3, gb3, sb5, gb5, sb7, gb7, wT, H);

    // hop 0
    mm_mfma_kernel<<<dim3(mm_grid, Wn), 256, 0, stream>>>(H, gwp, Th);
    agg_kernel<false><<<60000, 256, 0, stream>>>(
        Th, pairs, offs, gcnb, nullptr, H);

    // hop 1
    mm_mfma_kernel<<<dim3(mm_grid, Wn), 256, 0, stream>>>(
        H, gwp + (size_t)Wn * 4096, Th2);
    if (direct_out) {
        agg_kernel<true><<<60000, 256, 0, stream>>>(
            Th2, pairs, offs, gcnb + (size_t)Wn * Cn, x, out);
    } else {
        agg_kernel<true><<<60000, 256, 0, stream>>>(
            Th2, pairs, offs, gcnb + (size_t)Wn * Cn, x, H);
        hipMemcpyAsync(out, H, WNC * sizeof(float), hipMemcpyDeviceToDevice, stream);
    }
}

// Round 16
// 528.596 us; speedup vs baseline: 1.1129x; 1.0285x over previous
//
#include <hip/hip_runtime.h>
#include <hip/hip_fp16.h>
#include <cstddef>

#define Wn 12
#define Nn 20000
#define Cn 64
#define En 320000
#define OFFS_STRIDE 20032
#define NBKT 79
#define BCAP 4672

typedef _Float16 h4v __attribute__((ext_vector_type(4)));
typedef _Float16 h8v __attribute__((ext_vector_type(8)));
typedef float    f4v __attribute__((ext_vector_type(4)));

__device__ __forceinline__ float elu_f(float v) {
    return v > 0.f ? v : (expf(v) - 1.f);
}

// ---------------------------------------------------------------------------
// Weight prep: pack all 4 kernel sizes (sig+gate) into MFMA B-fragment order.
// ---------------------------------------------------------------------------
__global__ __launch_bounds__(256) void wprep_kernel(
    const float* __restrict__ sw1, const float* __restrict__ gw1,
    const float* __restrict__ sw3, const float* __restrict__ gw3,
    const float* __restrict__ sw5, const float* __restrict__ gw5,
    const float* __restrict__ sw7, const float* __restrict__ gw7,
    __half* __restrict__ dst)
{
    const int i = blockIdx.x * 256 + threadIdx.x;   // 32768 total
    if (i >= 32768) return;
    const int j    = i & 7;
    const int lane = (i >> 3) & 63;
    const int slot = i >> 9;                        // 0..63
    int g, loc;
    if (slot < 4)       { g = 0; loc = slot; }
    else if (slot < 16) { g = 1; loc = slot - 4; }
    else if (slot < 36) { g = 2; loc = slot - 16; }
    else                { g = 3; loc = slot - 36; }
    const int k   = 2 * g + 1;
    const int nks = 2 * k;                          // k-steps per path
    const int sg  = (loc >= nks) ? 1 : 0;          // 0 = sig, 1 = gate
    const int s   = loc - sg * nks;
    const int t   = s >> 1;                         // tap 0..k-1
    const int ih  = s & 1;                          // ic half
    const int oc  = lane & 15;
    const int ic  = ih * 32 + (lane >> 4) * 8 + j;
    const float* src;
    switch (g * 2 + sg) {
      case 0: src = sw1; break; case 1: src = gw1; break;
      case 2: src = sw3; break; case 3: src = gw3; break;
      case 4: src = sw5; break; case 5: src = gw5; break;
      case 6: src = sw7; break; default: src = gw7; break;
    }
    dst[i] = __float2half(src[(oc * 64 + ic) * k + t]);
}

// ---------------------------------------------------------------------------
// GCN weight prep: pack gcn_w (both hops) into MFMA B-fragment fp16 layout.
// ---------------------------------------------------------------------------
__global__ __launch_bounds__(256) void gwprep_kernel(
    const float* __restrict__ gcnw, __half* __restrict__ dst)
{
    const int i = blockIdx.x * 256 + threadIdx.x;   // 98304 total
    if (i >= 98304) return;
    const int j      = i & 7;
    const int lane   = (i >> 3) & 63;
    const int kh     = (i >> 9) & 1;
    const int octile = (i >> 10) & 3;
    const int hw     = i >> 12;
    const int ic = (lane >> 4) * 8 + j + kh * 32;
    const int oc = octile * 16 + (lane & 15);
    dst[i] = __float2half(gcnw[(size_t)hw * 4096 + ic * 64 + oc]);
}

// ---------------------------------------------------------------------------
// One oc-group of the inception conv via MFMA. B-fragments read directly
// from global wT (64 KB, L2-resident). (256,4) bound: no spill (round-8).
// ---------------------------------------------------------------------------
template<int G>
__device__ __forceinline__ void mfma_group(
    const __half* __restrict__ wTg,    // global fragment-packed weights, group G
    const __half* __restrict__ xsh,
    const float* __restrict__ sb, const float* __restrict__ gb,
    float* __restrict__ h, int nb, int tid)
{
    constexpr int NKS = 2 * (2 * G + 1);
    const int lane = tid & 63;
    const int wv   = tid >> 6;                 // 0..3
    const int node16 = lane & 15;
    const int abase = node16 * 128;
    const int swz   = (lane & 7) << 4;
    const int aoff0 = abase + ((0  + (lane >> 4) * 16) ^ swz);
    const int aoff1 = abase + ((64 + (lane >> 4) * 16) ^ swz);

    f4v accS[3], accG[3];
    #pragma unroll
    for (int m = 0; m < 3; ++m) {
        accS[m] = (f4v){0.f, 0.f, 0.f, 0.f};
        accG[m] = (f4v){0.f, 0.f, 0.f, 0.f};
    }

    #pragma unroll
    for (int s2 = 0; s2 < 2 * G + 1; ++s2) {   // dw = s2 - G
        const int dw = s2 - G;
        #pragma unroll
        for (int ih = 0; ih < 2; ++ih) {
            const int s = s2 * 2 + ih;
            const h8v bs = *(const h8v*)&wTg[(s * 64 + lane) * 8];
            const h8v bg = *(const h8v*)&wTg[((NKS + s) * 64 + lane) * 8];
            const int laneoff = ih ? aoff1 : aoff0;
            #pragma unroll
            for (int m = 0; m < 3; ++m) {
                const int w  = wv * 3 + m;
                const int wp = w + dw;
                if (wp >= 0 && wp < Wn) {      // wave-uniform
                    const h8v a = *(const h8v*)((const char*)xsh + wp * 2048 + laneoff);
                    accS[m] = __builtin_amdgcn_mfma_f32_16x16x32_f16(a, bs, accS[m], 0, 0, 0);
                    accG[m] = __builtin_amdgcn_mfma_f32_16x16x32_f16(a, bg, accG[m], 0, 0, 0);
                }
            }
        }
    }

    const float sbv = sb[node16];
    const float gbv = gb[node16];
    const int oc = G * 16 + node16;
    #pragma unroll
    for (int m = 0; m < 3; ++m) {
        const int w = wv * 3 + m;
        #pragma unroll
        for (int r = 0; r < 4; ++r) {
            const int node = (lane >> 4) * 4 + r;
            const float sv = accS[m][r] + sbv;
            const float gv = accG[m][r] + gbv;
            const float rv = sv > 0.f ? sv : 0.f;
            const float sg = 1.f / (1.f + expf(-gv));
            h[((size_t)w * Nn + nb + node) * Cn + oc] = rv * sg;
        }
    }
}

// ---------------------------------------------------------------------------
// Inception gated temporal conv, MFMA (round-13 form — measured best total;
// round-14's group split caused partial-line writeback, reverted).
// ---------------------------------------------------------------------------
__global__ __launch_bounds__(256, 4) void inception_mfma_kernel(
    const float* __restrict__ x,
    const float* __restrict__ sb1, const float* __restrict__ gb1,
    const float* __restrict__ sb3, const float* __restrict__ gb3,
    const float* __restrict__ sb5, const float* __restrict__ gb5,
    const float* __restrict__ sb7, const float* __restrict__ gb7,
    const __half* __restrict__ wT,
    float* __restrict__ h)
{
    __shared__ __align__(16) __half xsh[12 * 16 * 64];   // 24,576 B
    const int tid = threadIdx.x;
    const int nb  = blockIdx.x * 16;

    const float4* xg = (const float4*)x;
    for (int i = tid; i < 3072; i += 256) {
        const int w = i >> 8, r = i & 255, node = r >> 4, c4 = r & 15;
        const float4 v = xg[((size_t)w * Nn + nb + node) * 16 + c4];
        h4v p = { (_Float16)v.x, (_Float16)v.y, (_Float16)v.z, (_Float16)v.w };
        const int off = w * 2048 + node * 128 + (((c4 << 3)) ^ ((node & 7) << 4));
        *(h4v*)((char*)xsh + off) = p;
    }
    __syncthreads();
    mfma_group<0>(wT,         xsh, sb1, gb1, h, nb, tid);
    mfma_group<1>(wT + 2048,  xsh, sb3, gb3, h, nb, tid);
    mfma_group<2>(wT + 8192,  xsh, sb5, gb5, h, nb, tid);
    mfma_group<3>(wT + 18432, xsh, sb7, gb7, h, nb, tid);
}

// ---------------------------------------------------------------------------
// Per-window (N x 64) @ (64 x 64) matmul via MFMA, v2: NO LDS. The A-frag
// is 8 consecutive fp32 of one H row -> two float4 global loads + inline
// cvt per fragment. B-frags from prepacked gwp (L2-resident). Tail guarded.
// ---------------------------------------------------------------------------
__global__ __launch_bounds__(256) void mm_mfma_kernel(
    const float* __restrict__ h, const __half* __restrict__ gwp,
    __half* __restrict__ t)
{
    const int w    = blockIdx.y;
    const int nb   = blockIdx.x * 64;
    const int tid  = threadIdx.x;
    const int lane = tid & 63;
    const int wv   = tid >> 6;                 // wave owns nodes wv*16..+16
    const int node = nb + wv * 16 + (lane & 15);
    const int nc   = (node < Nn) ? node : (Nn - 1);
    const float* hrow = h + ((size_t)w * Nn + nc) * 64 + (lane >> 4) * 8;

    const float4 q0a = *(const float4*)&hrow[0];
    const float4 q0b = *(const float4*)&hrow[4];
    const float4 q1a = *(const float4*)&hrow[32];
    const float4 q1b = *(const float4*)&hrow[36];
    const h8v a0 = { (_Float16)q0a.x, (_Float16)q0a.y, (_Float16)q0a.z, (_Float16)q0a.w,
                     (_Float16)q0b.x, (_Float16)q0b.y, (_Float16)q0b.z, (_Float16)q0b.w };
    const h8v a1 = { (_Float16)q1a.x, (_Float16)q1a.y, (_Float16)q1a.z, (_Float16)q1a.w,
                     (_Float16)q1b.x, (_Float16)q1b.y, (_Float16)q1b.z, (_Float16)q1b.w };

    const int node0 = nb + wv * 16 + (lane >> 4) * 4;
    #pragma unroll
    for (int ot = 0; ot < 4; ++ot) {
        const h8v b0 = *(const h8v*)&gwp[(((w * 4 + ot) * 2 + 0) * 64 + lane) * 8];
        const h8v b1 = *(const h8v*)&gwp[(((w * 4 + ot) * 2 + 1) * 64 + lane) * 8];
        f4v acc = (f4v){0.f, 0.f, 0.f, 0.f};
        acc = __builtin_amdgcn_mfma_f32_16x16x32_f16(a0, b0, acc, 0, 0, 0);
        acc = __builtin_amdgcn_mfma_f32_16x16x32_f16(a1, b1, acc, 0, 0, 0);
        const int oc = ot * 16 + (lane & 15);
        #pragma unroll
        for (int r = 0; r < 4; ++r) {
            const int nd = node0 + r;
            if (nd < Nn)
                t[((size_t)w * Nn + nd) * Cn + oc] = __float2half(acc[r]);
        }
    }
}

// ---------------------------------------------------------------------------
// Bucketed sort, phase A: bin 2560 edges/block into 79 coarse dst-buckets
// (dst>>8). Line-granular HBM writes via per-bucket contiguous runs.
// ---------------------------------------------------------------------------
__global__ __launch_bounds__(256) void bucketA_kernel(
    const int* __restrict__ ei, const float* __restrict__ ew,
    int* __restrict__ bcur, uint2* __restrict__ bstr)
{
    const int w   = blockIdx.y;
    const int tid = threadIdx.x;
    __shared__ uint2 compact[2560];
    __shared__ unsigned char bkid[2560];
    __shared__ int rcnt[NBKT], rbase[NBKT], sbase[NBKT];
    __shared__ int sc[128];

    const int* eis = ei + (size_t)w * 2 * En;
    const float* ews = ew + (size_t)w * En;
    const int e0 = blockIdx.x * 2560;

    if (tid < NBKT) rcnt[tid] = 0;
    __syncthreads();

    int myb[10], myr[10];
    uint2 mye[10];
    #pragma unroll
    for (int it = 0; it < 10; ++it) {
        const int e = e0 + it * 256 + tid;
        const int s = eis[e];
        const int d = eis[En + e];
        const float wt = ews[e];
        const int bk = d >> 8;
        myb[it] = bk;
        mye[it].x = (unsigned)s | ((unsigned)(d & 255) << 16);
        mye[it].y = __float_as_uint(wt);
        myr[it] = atomicAdd(&rcnt[bk], 1);
    }
    __syncthreads();
    if (tid < 128) sc[tid] = (tid < NBKT) ? rcnt[tid] : 0;
    __syncthreads();
    #pragma unroll
    for (int dlt = 1; dlt < 128; dlt <<= 1) {
        int t = (tid < 128 && tid >= dlt) ? sc[tid - dlt] : 0;
        __syncthreads();
        if (tid < 128) sc[tid] += t;
        __syncthreads();
    }
    if (tid < NBKT) {
        rbase[tid] = sc[tid] - rcnt[tid];                       // excl within block
        sbase[tid] = atomicAdd(&bcur[w * 80 + tid], rcnt[tid]); // segment in stream
    }
    __syncthreads();
    #pragma unroll
    for (int it = 0; it < 10; ++it) {
        const int p = rbase[myb[it]] + myr[it];
        compact[p] = mye[it];
        bkid[p] = (unsigned char)myb[it];
    }
    __syncthreads();
    for (int i = tid; i < 2560; i += 256) {
        const int bk = bkid[i];
        int off = sbase[bk] + (i - rbase[bk]);
        if (off >= BCAP) off = BCAP - 1;   // ~9 sigma guard, never expected
        bstr[((size_t)w * NBKT + bk) * BCAP + off] = compact[i];
    }
}

// ---------------------------------------------------------------------------
// Tiny scan over the 12 x 79 bucket counts -> exclusive bucket bases.
// ---------------------------------------------------------------------------
__global__ __launch_bounds__(768) void bscan_kernel(
    const int* __restrict__ bcur, int* __restrict__ bbase)
{
    const int lane = threadIdx.x & 63;
    const int w    = threadIdx.x >> 6;   // 0..11
    const int c0 = (lane < NBKT) ? bcur[w * 80 + lane] : 0;
    int s = c0;
    #pragma unroll
    for (int d = 1; d < 64; d <<= 1) {
        int t = __shfl_up(s, d);
        if (lane >= d) s += t;
    }
    const int tot0 = __shfl(s, 63);
    const int c1 = (lane + 64 < NBKT) ? bcur[w * 80 + 64 + lane] : 0;
    int s1 = c1;
    #pragma unroll
    for (int d = 1; d < 64; d <<= 1) {
        int t = __shfl_up(s1, d);
        if (lane >= d) s1 += t;
    }
    s1 += tot0;
    bbase[w * 80 + lane] = s - c0;
    if (lane + 64 < NBKT) bbase[w * 80 + 64 + lane] = s1 - c1;
}

// ---------------------------------------------------------------------------
// Bucketed sort, phase B: counting-sort one bucket, emit pairs + CSR offs.
// ---------------------------------------------------------------------------
__global__ __launch_bounds__(256) void bucketB_kernel(
    const uint2* __restrict__ bstr, const int* __restrict__ bcur,
    const int* __restrict__ bbase, int* __restrict__ offs,
    float2* __restrict__ pairs)
{
    const int bk = blockIdx.x, w = blockIdx.y;
    const int tid = threadIdx.x;
    __shared__ uint2 sorted[BCAP];
    __shared__ int lhist[256], lbase[256], wsum[4];
    int n = bcur[w * 80 + bk];
    if (n > BCAP) n = BCAP;
    const int gbase = bbase[w * 80 + bk];
    const uint2* src = bstr + ((size_t)w * NBKT + bk) * BCAP;

    lhist[tid] = 0;
    __syncthreads();

    constexpr int MAXE = (BCAP + 255) / 256;   // 19
    uint2 mye[MAXE];
    short myd[MAXE], myr[MAXE];
    #pragma unroll
    for (int it = 0; it < MAXE; ++it) {
        const int i = tid + it * 256;
        if (i < n) {
            const uint2 e = src[i];
            mye[it] = e;
            const int dl = (e.x >> 16) & 255;
            myd[it] = (short)dl;
            myr[it] = (short)atomicAdd(&lhist[dl], 1);
        }
    }
    __syncthreads();
    {
        const int lane = tid & 63, wv = tid >> 6;
        const int v = lhist[tid];
        int sum = v;
        #pragma unroll
        for (int dlt = 1; dlt < 64; dlt <<= 1) {
            int t = __shfl_up(sum, dlt);
            if (lane >= dlt) sum += t;
        }
        if (lane == 63) wsum[wv] = sum;
        __syncthreads();
        if (tid < 4) {
            int o = wsum[tid], s2 = o;
            #pragma unroll
            for (int dlt = 1; dlt < 4; dlt <<= 1) {
                int t = __shfl_up(s2, dlt);
                if (tid >= dlt) s2 += t;
            }
            wsum[tid] = s2 - o;            // exclusive across waves
        }
        __syncthreads();
        const int be = wsum[wv] + sum - v; // exclusive per-dst base
        lbase[tid] = be;
        const int d = bk * 256 + tid;
        if (d < Nn) offs[w * OFFS_STRIDE + d] = gbase + be;
        if (bk == NBKT - 1 && tid == 0) offs[w * OFFS_STRIDE + Nn] = En;
    }
    __syncthreads();
    #pragma unroll
    for (int it = 0; it < MAXE; ++it) {
        const int i = tid + it * 256;
        if (i < n)
            sorted[lbase[myd[it]] + myr[it]] = mye[it];
    }
    __syncthreads();
    float2* pw = pairs + (size_t)w * En + gbase;
    for (int i = tid; i < n; i += 256) {
        const uint2 e = sorted[i];
        pw[i] = make_float2(__int_as_float((int)(e.x & 0xFFFFu)), __uint_as_float(e.y));
    }
}

// ---------------------------------------------------------------------------
// Aggregation v6: v3r shape (16 lanes/edge x 4 subgroups, 4 ch/lane,
// 32-bit offsets) + a 16-edge outer unroll: 4 INDEPENDENT pair->gather->fma
// chains in flight (was 2). Rounds 9-12 showed the kernel is gather-latency
// bound (VALUBusy 62%, HBM 16%); v4/v5 failed by changing lane shape or
// adding hot-loop guards — this keeps the measured-best body and only
// deepens MLP. Falls through to the proven 8/4/1 tails.
// ---------------------------------------------------------------------------
template<bool LAST>
__global__ __launch_bounds__(256) void agg_kernel(
    const __half* __restrict__ t, const float2* __restrict__ pairs,
    const int* __restrict__ offs, const float* __restrict__ b,
    const float* __restrict__ x, float* __restrict__ out)
{
    const int blk = blockIdx.x;
    const int r = blk & 7, q = blk >> 3;
    int w, ng;
    if (q < 5000) { w = r; ng = q; }
    else { int q2 = q - 5000; w = 8 + (r >> 1); ng = q2 * 2 + (r & 1); }

    const int d    = ng * 4 + (threadIdx.x >> 6);
    const int lane = threadIdx.x & 63;
    const int eg   = lane >> 4;           // edge subgroup 0..3
    const int c4   = lane & 15;           // channel quad (4 channels)
    const int* ow  = offs + w * OFFS_STRIDE;
    const int beg = ow[d];
    const int end = ow[d + 1];
    const float2* pw = pairs + (size_t)w * En;
    const __half* twc = t + (size_t)w * Nn * Cn + c4 * 4;

    float a0 = 0.f, a1 = 0.f, a2 = 0.f, a3 = 0.f;
    int i = beg;
    for (; i + 16 <= end; i += 16) {
        const float2 p0 = pw[i + eg];
        const float2 p1 = pw[i + 4 + eg];
        const float2 p2 = pw[i + 8 + eg];
        const float2 p3 = pw[i + 12 + eg];
        const uint2 r0 = *(const uint2*)(twc + ((unsigned)__float_as_int(p0.x) << 6));
        const uint2 r1 = *(const uint2*)(twc + ((unsigned)__float_as_int(p1.x) << 6));
        const uint2 r2 = *(const uint2*)(twc + ((unsigned)__float_as_int(p2.x) << 6));
        const uint2 r3 = *(const uint2*)(twc + ((unsigned)__float_as_int(p3.x) << 6));
        const float2 f0a = __half22float2(*(const __half2*)&r0.x);
        const float2 f0b = __half22float2(*(const __half2*)&r0.y);
        const float2 f1a = __half22float2(*(const __half2*)&r1.x);
        const float2 f1b = __half22float2(*(const __half2*)&r1.y);
        const float2 f2a = __half22float2(*(const __half2*)&r2.x);
        const float2 f2b = __half22float2(*(const __half2*)&r2.y);
        const float2 f3a = __half22float2(*(const __half2*)&r3.x);
        const float2 f3b = __half22float2(*(const __half2*)&r3.y);
        a0 = fmaf(p0.y, f0a.x, a0); a1 = fmaf(p0.y, f0a.y, a1);
        a2 = fmaf(p0.y, f0b.x, a2); a3 = fmaf(p0.y, f0b.y, a3);
        a0 = fmaf(p1.y, f1a.x, a0); a1 = fmaf(p1.y, f1a.y, a1);
        a2 = fmaf(p1.y, f1b.x, a2); a3 = fmaf(p1.y, f1b.y, a3);
        a0 = fmaf(p2.y, f2a.x, a0); a1 = fmaf(p2.y, f2a.y, a1);
        a2 = fmaf(p2.y, f2b.x, a2); a3 = fmaf(p2.y, f2b.y, a3);
        a0 = fmaf(p3.y, f3a.x, a0); a1 = fmaf(p3.y, f3a.y, a1);
        a2 = fmaf(p3.y, f3b.x, a2); a3 = fmaf(p3.y, f3b.y, a3);
    }
    if (i + 8 <= end) {
        const float2 p0 = pw[i + eg];
        const float2 p1 = pw[i + 4 + eg];
        const uint2 r0 = *(const uint2*)(twc + ((unsigned)__float_as_int(p0.x) << 6));
        const uint2 r1 = *(const uint2*)(twc + ((unsigned)__float_as_int(p1.x) << 6));
        const float2 f0a = __half22float2(*(const __half2*)&r0.x);
        const float2 f0b = __half22float2(*(const __half2*)&r0.y);
        const float2 f1a = __half22float2(*(const __half2*)&r1.x);
        const float2 f1b = __half22float2(*(const __half2*)&r1.y);
        a0 = fmaf(p0.y, f0a.x, a0); a1 = fmaf(p0.y, f0a.y, a1);
        a2 = fmaf(p0.y, f0b.x, a2); a3 = fmaf(p0.y, f0b.y, a3);
        a0 = fmaf(p1.y, f1a.x, a0); a1 = fmaf(p1.y, f1a.y, a1);
        a2 = fmaf(p1.y, f1b.x, a2); a3 = fmaf(p1.y, f1b.y, a3);
        i += 8;
    }
    if (i + 4 <= end) {
        const float2 p0 = pw[i + eg];
        const uint2 r0 = *(const uint2*)(twc + ((unsigned)__float_as_int(p0.x) << 6));
        const float2 f0a = __half22float2(*(const __half2*)&r0.x);
        const float2 f0b = __half22float2(*(const __half2*)&r0.y);
        a0 = fmaf(p0.y, f0a.x, a0); a1 = fmaf(p0.y, f0a.y, a1);
        a2 = fmaf(p0.y, f0b.x, a2); a3 = fmaf(p0.y, f0b.y, a3);
        i += 4;
    }
    if (i + eg < end) {
        const float2 p0 = pw[i + eg];
        const uint2 r0 = *(const uint2*)(twc + ((unsigned)__float_as_int(p0.x) << 6));
        const float2 f0a = __half22float2(*(const __half2*)&r0.x);
        const float2 f0b = __half22float2(*(const __half2*)&r0.y);
        a0 = fmaf(p0.y, f0a.x, a0); a1 = fmaf(p0.y, f0a.y, a1);
        a2 = fmaf(p0.y, f0b.x, a2); a3 = fmaf(p0.y, f0b.y, a3);
    }

    a0 += __shfl_xor(a0, 16); a0 += __shfl_xor(a0, 32);
    a1 += __shfl_xor(a1, 16); a1 += __shfl_xor(a1, 32);
    a2 += __shfl_xor(a2, 16); a2 += __shfl_xor(a2, 32);
    a3 += __shfl_xor(a3, 16); a3 += __shfl_xor(a3, 32);

    if (eg == 0) {
        const float4 bv = *(const float4*)&b[w * Cn + c4 * 4];
        float v0 = elu_f(a0 + bv.x);
        float v1 = elu_f(a1 + bv.y);
        float v2 = elu_f(a2 + bv.z);
        float v3 = elu_f(a3 + bv.w);
        const size_t oi = ((size_t)w * Nn + d) * Cn + c4 * 4;
        if (LAST) {
            const float4 xv = *(const float4*)&x[oi];
            v0 += xv.x; v1 += xv.y; v2 += xv.z; v3 += xv.w;
        }
        *(float4*)&out[oi] = make_float4(v0, v1, v2, v3);
    }
}

// ---------------------------------------------------------------------------
// ws layout (floats):
//   [0)           pairs : 7,680,000
//   [7,680,000)   offs  :   240,384 (int)
//   [7,920,384)   bcur  :   240,000 (int)
//   [8,160,384)   wTreg :   240,000 (int)  -- wT + gwp fragment packs
//   [8,400,384)   H     : 15,360,000      -- doubles as bstr before inception
//   [23,760,384)  Th2   : 7,680,000       -- hop-1 fp16 t (if ws fits);
//                                            enables direct agg->d_out write.
// ---------------------------------------------------------------------------
extern "C" void kernel_launch(void* const* d_in, const int* in_sizes, int n_in,
                              void* d_out, int out_size, void* d_ws, size_t ws_size,
                              hipStream_t stream)
{
    const float* x    = (const float*)d_in[0];
    const int*   ei   = (const int*)d_in[1];
    const float* ew   = (const float*)d_in[2];
    const float* sw1  = (const float*)d_in[3];
    const float* sb1  = (const float*)d_in[4];
    const float* gw1  = (const float*)d_in[5];
    const float* gb1  = (const float*)d_in[6];
    const float* sw3  = (const float*)d_in[7];
    const float* sb3  = (const float*)d_in[8];
    const float* gw3  = (const float*)d_in[9];
    const float* gb3  = (const float*)d_in[10];
    const float* sw5  = (const float*)d_in[11];
    const float* sb5  = (const float*)d_in[12];
    const float* gw5  = (const float*)d_in[13];
    const float* gb5  = (const float*)d_in[14];
    const float* sw7  = (const float*)d_in[15];
    const float* sb7  = (const float*)d_in[16];
    const float* gw7  = (const float*)d_in[17];
    const float* gb7  = (const float*)d_in[18];
    const float* gcnw = (const float*)d_in[19];
    const float* gcnb = (const float*)d_in[20];
    float* out = (float*)d_out;
    __half* Th = (__half*)d_out;

    const size_t WNC = (size_t)Wn * Nn * Cn;
    const int mm_grid = (Nn + 63) / 64;    // 313 — tail block guarded

    float2* pairs = (float2*)d_ws;
    int*    offs  = (int*)((float*)d_ws + 7680000);
    int*    bcur  = offs + 240384;
    int*    bbase = bcur + 1024;
    __half* wT    = (__half*)(bcur + 240000);
    __half* gwp   = wT + 32768;
    float*  H     = (float*)((int*)(bcur + 240000) + 240000);
    uint2*  bstr  = (uint2*)H;             // phase-A bucket streams (dead after B)

    // hop-1 t placement: dedicated ws region if it fits, else d_out + memcpy
    const size_t need_ws_bytes = (size_t)(23760384 + 7680000) * sizeof(float);
    const bool   direct_out    = ws_size >= need_ws_bytes;
    __half* Th2 = direct_out ? (__half*)((float*)d_ws + 23760384) : Th;

    // --- sort preamble ---
    hipMemsetAsync(bcur, 0, (size_t)Wn * 80 * sizeof(int), stream);
    bucketA_kernel<<<dim3(En / 2560, Wn), 256, 0, stream>>>(ei, ew, bcur, bstr);
    bscan_kernel<<<1, 768, 0, stream>>>(bcur, bbase);
    bucketB_kernel<<<dim3(NBKT, Wn), 256, 0, stream>>>(bstr, bcur, bbase, offs, pairs);

    // --- weight fragment packs (fp16) ---
    wprep_kernel<<<128, 256, 0, stream>>>(sw1, gw1, sw3, gw3, sw5, gw5, sw7, gw7, wT);
    gwprep_kernel<<<384, 256, 0, stream>>>(gcnw, gwp);

    // --- feature path (MFMA) ---
    inception_mfma_kernel<<<Nn / 16, 256, 0, stream>>>(
        x, sb1, gb1, sb3, gb3, sb5, gb5, sb7, gb7, wT, H);

    // hop 0
    mm_mfma_kernel<<<dim3(mm_grid, Wn), 256, 0, stream>>>(H, gwp, Th);
    agg_kernel<false><<<60000, 256, 0, stream>>>(
        Th, pairs, offs, gcnb, nullptr, H);

    // hop 1
    mm_mfma_kernel<<<dim3(mm_grid, Wn), 256, 0, stream>>>(
        H, gwp + (size_t)Wn * 4096, Th2);
    if (direct_out) {
        agg_kernel<true><<<60000, 256, 0, stream>>>(
            Th2, pairs, offs, gcnb + (size_t)Wn * Cn, x, out);
    } else {
        agg_kernel<true><<<60000, 256, 0, stream>>>(
            Th2, pairs, offs, gcnb + (size_t)Wn * Cn, x, H);
        hipMemcpyAsync(out, H, WNC * sizeof(float), hipMemcpyDeviceToDevice, stream);
    }
}